// Round 26
// baseline (68.315 us; speedup 1.0000x reference)
//
#include <hip/hip_runtime.h>

// Chamfer distance via exact grid NN — two-phase query (bound + exact window).
// pts = img_render_points[0]      : 4096 x 2 f32 (slice 0)
// refs = ref_catheter_skeleton[1] : 32768 x 2 f32 (last slice; flip is neutral)
//
// R22-R25 lesson: expanding-ring while-loops serialize dependent loads along
// some axis every time. New query: phase 1 scans the center cell (quad-split,
// actual distance d0); rare empty-center path expands rings but loads real
// points (bound always an actual distance -> exact & clamp-safe). Phase 2
// scans the rectangular cell window covering disc(q,d0) — bounds known before
// the loop, cells quad-uniform, points quad-split coalesced unroll-2. Exact.

constexpr int N_PTS = 4096;
constexpr int M_REF = 32768;
constexpr float EXT = 512.f;
// refs grid (searched by pt-queries)
constexpr int   GSR = 128, NCR = GSR * GSR;
constexpr float CSR = 8.f, INV_CSR = 0.125f;
constexpr int   CAPR = 80;      // lambda_center ~33, +8sigma (proven)
// pts grid (searched by ref-queries)
constexpr int   GSP = 64, NCP = GSP * GSP;
constexpr float CSP = 16.f, INV_CSP = 0.0625f;
constexpr int   CAPP = 64;      // lambda_center ~17, +11sigma

// ---------------- Kernel 0: zero counters (80 x 256 = 20480 uints) ---------
__global__ __launch_bounds__(256) void zero_kernel(unsigned int* __restrict__ cnt)
{
    cnt[blockIdx.x * 256 + threadIdx.x] = 0u;   // cntR[NCR] + cntP[NCP]
}

// ---------------- Kernel 1: build both grids (144 x 256) -------------------
__global__ __launch_bounds__(256) void build_kernel(
    const float2* __restrict__ pts, const float2* __restrict__ refs,
    unsigned int* __restrict__ cntR, unsigned int* __restrict__ cntP,
    float2* __restrict__ bufR, float2* __restrict__ bufP,
    float* __restrict__ out)
{
    const int t = blockIdx.x * 256 + threadIdx.x;   // 36864
    if (t == 0) out[0] = 0.f;                       // zero accumulator
    if (t < N_PTS) {
        const float2 p = pts[t];
        const int cx = min(GSP - 1, max(0, (int)floorf((p.x + EXT) * INV_CSP)));
        const int cy = min(GSP - 1, max(0, (int)floorf((p.y + EXT) * INV_CSP)));
        const int c = cy * GSP + cx;
        const unsigned int s = atomicAdd(&cntP[c], 1u);
        if (s < CAPP) bufP[c * CAPP + s] = p;
    } else {
        const float2 p = refs[t - N_PTS];
        const int cx = min(GSR - 1, max(0, (int)floorf((p.x + EXT) * INV_CSR)));
        const int cy = min(GSR - 1, max(0, (int)floorf((p.y + EXT) * INV_CSR)));
        const int c = cy * GSR + cx;
        const unsigned int s = atomicAdd(&cntR[c], 1u);
        if (s < CAPR) bufR[c * CAPR + s] = p;
    }
}

// ---------------- Kernel 2: two-phase queries (576 x 256) ------------------
// Blocks 0..63: pt queries vs refs grid. Blocks 64..575: ref queries vs pts
// grid. 4 lanes per query. Count tables in LDS (packed-byte staging).
__global__ __launch_bounds__(256) void query_kernel(
    const float2* __restrict__ pts, const float2* __restrict__ refs,
    const unsigned int* __restrict__ cntR, const unsigned int* __restrict__ cntP,
    const float2* __restrict__ bufR, const float2* __restrict__ bufP,
    float* __restrict__ out)
{
    __shared__ unsigned char cnt8[NCR];   // 16 KB (pt blocks) / 4 KB (ref blocks)
    __shared__ float ssum[4];
    const int tid = threadIdx.x;
    const bool isPt = (blockIdx.x < 64);  // block-uniform

    // Stage counts as packed bytes (uint writes: no byte-store conflicts).
    {
        const unsigned int* src = isPt ? cntR : cntP;
        const int nIter = (isPt ? NCR : NCP) / 1024;
        for (int i = 0; i < nIter; ++i) {
            const uint4 v = ((const uint4*)src)[tid + 256 * i];
            ((unsigned int*)cnt8)[tid + 256 * i] =
                min(v.x, 255u) | (min(v.y, 255u) << 8) |
                (min(v.z, 255u) << 16) | (min(v.w, 255u) << 24);
        }
    }
    __syncthreads();

    const int qi = tid & 3;
    int GS, cap; float INVg;
    const float2* buf;
    float2 q;
    if (isPt) {
        q = pts[blockIdx.x * 64 + (tid >> 2)];
        buf = bufR; GS = GSR; cap = CAPR; INVg = INV_CSR;
    } else {
        q = refs[(blockIdx.x - 64) * 64 + (tid >> 2)];
        buf = bufP; GS = GSP; cap = CAPP; INVg = INV_CSP;
    }

    const int cx = min(GS - 1, max(0, (int)floorf((q.x + EXT) * INVg)));
    const int cy = min(GS - 1, max(0, (int)floorf((q.y + EXT) * INVg)));
    float best = 3.0e38f;

    // ---- Phase 1: center cell (quad-split, coalesced, unroll-2) ----------
    {
        const int c = cy * GS + cx;
        const int n = min((int)cnt8[c], cap);
        const float2* bb = buf + c * cap;
        int s = qi;
        for (; s + 4 < n; s += 8) {
            const float2 r0 = bb[s], r1 = bb[s + 4];
            const float dx0 = q.x - r0.x, dy0 = q.y - r0.y;
            const float dx1 = q.x - r1.x, dy1 = q.y - r1.y;
            best = fminf(best, fmaf(dx0, dx0, dy0 * dy0));
            best = fminf(best, fmaf(dx1, dx1, dy1 * dy1));
        }
        if (s < n) {
            const float2 r = bb[s];
            const float dx = q.x - r.x, dy = q.y - r.y;
            best = fminf(best, fmaf(dx, dx, dy * dy));
        }
    }
    best = fminf(best, __shfl_xor(best, 1, 64));
    best = fminf(best, __shfl_xor(best, 2, 64));

    // Rare: empty center -> expand rings, loading REAL points (exact bound).
    if (best > 1e37f) {
        for (int k = 1; k < GS; ++k) {
            for (int i = qi; i < 8 * k; i += 4) {
                const int side = i / (2 * k), off = i % (2 * k);
                int ccx, ccy;
                if      (side == 0) { ccx = cx - k + off; ccy = cy - k; }
                else if (side == 1) { ccx = cx + k; ccy = cy - k + off; }
                else if (side == 2) { ccx = cx + k - off; ccy = cy + k; }
                else                { ccx = cx - k; ccy = cy + k - off; }
                if (ccx < 0 || ccx >= GS || ccy < 0 || ccy >= GS) continue;
                const int c = ccy * GS + ccx;
                const int n = min((int)cnt8[c], cap);
                const float2* bb = buf + c * cap;
                for (int s = 0; s < n; ++s) {
                    const float2 r = bb[s];
                    const float dx = q.x - r.x, dy = q.y - r.y;
                    best = fminf(best, fmaf(dx, dx, dy * dy));
                }
            }
            best = fminf(best, __shfl_xor(best, 1, 64));
            best = fminf(best, __shfl_xor(best, 2, 64));
            const bool covered = (cx - k <= 0) && (cy - k <= 0) &&
                                 (cx + k >= GS - 1) && (cy + k >= GS - 1);
            if (best < 1e37f || covered) break;
        }
    }

    // ---- Phase 2: exact rectangular window covering disc(q, d0) ----------
    const float d0 = sqrtf(fmaxf(best, 0.f)) * 1.0001f + 1e-3f;
    const int xlo = max(0, (int)floorf((q.x - d0 + EXT) * INVg));
    const int xhi = min(GS - 1, (int)floorf((q.x + d0 + EXT) * INVg));
    const int ylo = max(0, (int)floorf((q.y - d0 + EXT) * INVg));
    const int yhi = min(GS - 1, (int)floorf((q.y + d0 + EXT) * INVg));
    for (int yy = ylo; yy <= yhi; ++yy) {
        for (int xx = xlo; xx <= xhi; ++xx) {
            const int c = yy * GS + xx;
            const int n = min((int)cnt8[c], cap);
            if (!n) continue;
            const float2* bb = buf + c * cap;
            int s = qi;
            for (; s + 4 < n; s += 8) {
                const float2 r0 = bb[s], r1 = bb[s + 4];
                const float dx0 = q.x - r0.x, dy0 = q.y - r0.y;
                const float dx1 = q.x - r1.x, dy1 = q.y - r1.y;
                best = fminf(best, fmaf(dx0, dx0, dy0 * dy0));
                best = fminf(best, fmaf(dx1, dx1, dy1 * dy1));
            }
            if (s < n) {
                const float2 r = bb[s];
                const float dx = q.x - r.x, dy = q.y - r.y;
                best = fminf(best, fmaf(dx, dx, dy * dy));
            }
        }
    }
    best = fminf(best, __shfl_xor(best, 1, 64));
    best = fminf(best, __shfl_xor(best, 2, 64));

    float d = (qi == 0) ? sqrtf(fmaxf(best, 1e-12f)) : 0.f;
    #pragma unroll
    for (int off = 32; off > 0; off >>= 1) d += __shfl_down(d, off, 64);
    const int lane = tid & 63, wave = tid >> 6;
    if (lane == 0) ssum[wave] = d;
    __syncthreads();
    if (tid == 0) atomicAdd(out, ssum[0] + ssum[1] + ssum[2] + ssum[3]);
}

extern "C" void kernel_launch(void* const* d_in, const int* in_sizes, int n_in,
                              void* d_out, int out_size, void* d_ws, size_t ws_size,
                              hipStream_t stream) {
    const float2* pts  = (const float2*)d_in[0];            // circle 0 (offset 0)
    const float2* refs = ((const float2*)d_in[1]) + M_REF;  // last (=2nd) skeleton slice

    unsigned int* cntR = (unsigned int*)d_ws;               // [NCR]
    unsigned int* cntP = cntR + NCR;                        // [NCP]
    float2* bufR = (float2*)(cntP + NCP);                   // [NCR*CAPR] 10.5 MB
    float2* bufP = bufR + NCR * CAPR;                       // [NCP*CAPP]  2 MB
    float* out = (float*)d_out;

    zero_kernel <<<(NCR + NCP) / 256, 256, 0, stream>>>(cntR);  // 80 blocks
    build_kernel<<<144, 256, 0, stream>>>(pts, refs, cntR, cntP, bufR, bufP, out);
    query_kernel<<<576, 256, 0, stream>>>(pts, refs, cntR, cntP, bufR, bufP, out);
}

// Round 27
// 47.037 us; speedup vs baseline: 1.4524x; 1.4524x over previous
//
#include <hip/hip_runtime.h>

// Chamfer distance via exact grid NN — R23 ring structure + in-cell MLP.
// pts = img_render_points[0]      : 4096 x 2 f32 (slice 0)
// refs = ref_catheter_skeleton[1] : 32768 x 2 f32 (last slice; flip is neutral)
//
// Grid history: R23/R24 (cells quad-split, points serial) query ~39us;
// R25 (points split, cells serial) 47; R26 (two-phase) 53. Root residual of
// the best form: one lane issues n SERIAL dependent loads per cell. Fix:
// unroll-4 batched loads within each cell (MLP x4). pts grid 64x64 cs=16
// (lambda~17, CAPP=64 ~ +11sigma) shrinks the dominant center-cell scan.
// Ring termination bound and all reductions unchanged (absmax 0.0 proven).

constexpr int N_PTS = 4096;
constexpr int M_REF = 32768;
constexpr float EXT = 512.f;
// refs grid (searched by pt-queries)
constexpr int   GSR = 128, NCR = GSR * GSR;
constexpr float CSR = 8.f, INV_CSR = 0.125f;
constexpr int   CAPR = 80;      // lambda_center ~33, +8sigma (proven)
// pts grid (searched by ref-queries)
constexpr int   GSP = 64, NCP = GSP * GSP;
constexpr float CSP = 16.f, INV_CSP = 0.0625f;
constexpr int   CAPP = 64;      // lambda_center ~17, +11sigma

// ---------------- Kernel 0: zero counters (80 x 256 = 20480 uints) ---------
__global__ __launch_bounds__(256) void zero_kernel(unsigned int* __restrict__ cnt)
{
    cnt[blockIdx.x * 256 + threadIdx.x] = 0u;   // cntR[NCR] + cntP[NCP]
}

// ---------------- Kernel 1: build both grids (144 x 256) -------------------
__global__ __launch_bounds__(256) void build_kernel(
    const float2* __restrict__ pts, const float2* __restrict__ refs,
    unsigned int* __restrict__ cntR, unsigned int* __restrict__ cntP,
    float2* __restrict__ bufR, float2* __restrict__ bufP,
    float* __restrict__ out)
{
    const int t = blockIdx.x * 256 + threadIdx.x;   // 36864
    if (t == 0) out[0] = 0.f;                       // zero accumulator
    if (t < N_PTS) {
        const float2 p = pts[t];
        const int cx = min(GSP - 1, max(0, (int)floorf((p.x + EXT) * INV_CSP)));
        const int cy = min(GSP - 1, max(0, (int)floorf((p.y + EXT) * INV_CSP)));
        const int c = cy * GSP + cx;
        const unsigned int s = atomicAdd(&cntP[c], 1u);
        if (s < CAPP) bufP[c * CAPP + s] = p;       // overflow ~1e-20
    } else {
        const float2 p = refs[t - N_PTS];
        const int cx = min(GSR - 1, max(0, (int)floorf((p.x + EXT) * INV_CSR)));
        const int cy = min(GSR - 1, max(0, (int)floorf((p.y + EXT) * INV_CSR)));
        const int c = cy * GSR + cx;
        const unsigned int s = atomicAdd(&cntR[c], 1u);
        if (s < CAPR) bufR[c * CAPR + s] = p;       // overflow ~1e-13
    }
}

// ---------------- Kernel 2: ring-search queries (576 x 256) ----------------
// Blocks 0..63: pt queries vs refs grid. Blocks 64..575: ref queries vs pts
// grid. 4 lanes/query: ring cells quad-split; in-cell loads unroll-4 (MLP).
__global__ __launch_bounds__(256) void query_kernel(
    const float2* __restrict__ pts, const float2* __restrict__ refs,
    const unsigned int* __restrict__ cntR, const unsigned int* __restrict__ cntP,
    const float2* __restrict__ bufR, const float2* __restrict__ bufP,
    float* __restrict__ out)
{
    __shared__ unsigned char cnt8[NCR];   // 16 KB (pt blocks) / 4 KB (ref blocks)
    __shared__ float ssum[4];
    const int tid = threadIdx.x;
    const bool isPt = (blockIdx.x < 64);  // block-uniform

    // Stage counts as packed bytes (uint4 reads, uint writes — proven R26).
    {
        const unsigned int* src = isPt ? cntR : cntP;
        const int nIter = (isPt ? NCR : NCP) / 1024;
        for (int i = 0; i < nIter; ++i) {
            const uint4 v = ((const uint4*)src)[tid + 256 * i];
            ((unsigned int*)cnt8)[tid + 256 * i] =
                min(v.x, 255u) | (min(v.y, 255u) << 8) |
                (min(v.z, 255u) << 16) | (min(v.w, 255u) << 24);
        }
    }
    __syncthreads();

    const int qi = tid & 3;
    int GS, cap; float CSg, INVg;
    const float2* buf;
    float2 q;
    if (isPt) {
        q = pts[blockIdx.x * 64 + (tid >> 2)];
        buf = bufR; GS = GSR; cap = CAPR; CSg = CSR; INVg = INV_CSR;
    } else {
        q = refs[(blockIdx.x - 64) * 64 + (tid >> 2)];
        buf = bufP; GS = GSP; cap = CAPP; CSg = CSP; INVg = INV_CSP;
    }

    const int cx = min(GS - 1, max(0, (int)floorf((q.x + EXT) * INVg)));
    const int cy = min(GS - 1, max(0, (int)floorf((q.y + EXT) * INVg)));
    float best = 3.0e38f;                           // squared distance

    for (int k = 0; ; ++k) {
        const int ncell = k ? 8 * k : 1;
        for (int i = qi; i < ncell; i += 4) {       // cells quad-split (R23)
            int ccx, ccy;
            if (k == 0) { ccx = cx; ccy = cy; }
            else {
                const int side = i / (2 * k), off = i % (2 * k);
                if      (side == 0) { ccx = cx - k + off; ccy = cy - k; }
                else if (side == 1) { ccx = cx + k; ccy = cy - k + off; }
                else if (side == 2) { ccx = cx + k - off; ccy = cy + k; }
                else                { ccx = cx - k; ccy = cy + k - off; }
            }
            if (ccx < 0 || ccx >= GS || ccy < 0 || ccy >= GS) continue;
            const int c = ccy * GS + ccx;
            int n = (int)cnt8[c];                   // LDS probe: ~cycles
            if (n == 0) continue;
            n = min(n, cap);
            const float2* bb = buf + c * cap;
            // Unroll-4: 4 independent loads in flight (MLP), then 4 mins.
            int s = 0;
            for (; s + 3 < n; s += 4) {
                const float2 r0 = bb[s],     r1 = bb[s + 1];
                const float2 r2 = bb[s + 2], r3 = bb[s + 3];
                const float dx0 = q.x - r0.x, dy0 = q.y - r0.y;
                const float dx1 = q.x - r1.x, dy1 = q.y - r1.y;
                const float dx2 = q.x - r2.x, dy2 = q.y - r2.y;
                const float dx3 = q.x - r3.x, dy3 = q.y - r3.y;
                best = fminf(best, fmaf(dx0, dx0, dy0 * dy0));
                best = fminf(best, fmaf(dx1, dx1, dy1 * dy1));
                best = fminf(best, fmaf(dx2, dx2, dy2 * dy2));
                best = fminf(best, fmaf(dx3, dx3, dy3 * dy3));
            }
            for (; s < n; ++s) {
                const float2 r = bb[s];
                const float dx = q.x - r.x, dy = q.y - r.y;
                best = fminf(best, fmaf(dx, dx, dy * dy));
            }
        }
        // Quad-consensus min (xor 1,2 stay within the quad).
        best = fminf(best, __shfl_xor(best, 1, 64));
        best = fminf(best, __shfl_xor(best, 2, 64));
        // Exact termination: unscanned points lie outside the scanned box.
        const float blox = (cx - k) * CSg - EXT, bhix = (cx + k + 1) * CSg - EXT;
        const float bloy = (cy - k) * CSg - EXT, bhiy = (cy + k + 1) * CSg - EXT;
        const float lb = fminf(fminf(q.x - blox, bhix - q.x),
                               fminf(q.y - bloy, bhiy - q.y));
        const bool covered = (cx - k <= 0) && (cy - k <= 0) &&
                             (cx + k >= GS - 1) && (cy + k >= GS - 1);
        if (covered || (lb > 0.f && best <= lb * lb)) break;
    }

    float d = (qi == 0) ? sqrtf(fmaxf(best, 1e-12f)) : 0.f;
    #pragma unroll
    for (int off = 32; off > 0; off >>= 1) d += __shfl_down(d, off, 64);
    const int lane = tid & 63, wave = tid >> 6;
    if (lane == 0) ssum[wave] = d;
    __syncthreads();
    if (tid == 0) atomicAdd(out, ssum[0] + ssum[1] + ssum[2] + ssum[3]);
}

extern "C" void kernel_launch(void* const* d_in, const int* in_sizes, int n_in,
                              void* d_out, int out_size, void* d_ws, size_t ws_size,
                              hipStream_t stream) {
    const float2* pts  = (const float2*)d_in[0];            // circle 0 (offset 0)
    const float2* refs = ((const float2*)d_in[1]) + M_REF;  // last (=2nd) skeleton slice

    unsigned int* cntR = (unsigned int*)d_ws;               // [NCR]
    unsigned int* cntP = cntR + NCR;                        // [NCP]
    float2* bufR = (float2*)(cntP + NCP);                   // [NCR*CAPR] 10.5 MB
    float2* bufP = bufR + NCR * CAPR;                       // [NCP*CAPP]  2 MB
    float* out = (float*)d_out;

    zero_kernel <<<(NCR + NCP) / 256, 256, 0, stream>>>(cntR);  // 80 blocks
    build_kernel<<<144, 256, 0, stream>>>(pts, refs, cntR, cntP, bufR, bufP, out);
    query_kernel<<<576, 256, 0, stream>>>(pts, refs, cntR, cntP, bufR, bufP, out);
}